// Round 1
// baseline (9032.919 us; speedup 1.0000x reference)
//
#include <hip/hip_runtime.h>
#include <cstdint>
#include <cstddef>

#define NF 16
#define DIM 32

// ---------------- scatter: agg[dst] += x[src]  (16-dim, layer 1) ----------------
__global__ void scatter16_k(const float* __restrict__ x, const int* __restrict__ ei,
                            float* __restrict__ agg, int n_edges) {
    int tid = blockIdx.x * blockDim.x + threadIdx.x;
    int e = tid >> 2;
    if (e >= n_edges) return;
    int q = (tid & 3) * 4;
    int src = ei[e];
    int dst = ei[n_edges + e];
    float4 v = *(const float4*)(x + (size_t)src * NF + q);
    float* p = agg + (size_t)dst * NF + q;
    unsafeAtomicAdd(p + 0, v.x);
    unsafeAtomicAdd(p + 1, v.y);
    unsafeAtomicAdd(p + 2, v.z);
    unsafeAtomicAdd(p + 3, v.w);
}

// ---------------- scatter: agg[dst] += bn(h[src])  (32-dim, layers 2,3) ----------------
// ab[0..31] = scale a, ab[32..63] = shift b  (bn(x) = a*x + b)
__global__ void scatter32_bn_k(const float* __restrict__ h, const int* __restrict__ ei,
                               const float* __restrict__ ab, float* __restrict__ agg,
                               int n_edges) {
    int tid = blockIdx.x * blockDim.x + threadIdx.x;
    int e = tid >> 3;
    if (e >= n_edges) return;
    int q = (tid & 7) * 4;
    int src = ei[e];
    int dst = ei[n_edges + e];
    float4 v = *(const float4*)(h + (size_t)src * DIM + q);
    float4 a = *(const float4*)(ab + q);
    float4 b = *(const float4*)(ab + DIM + q);
    v.x = fmaf(a.x, v.x, b.x);
    v.y = fmaf(a.y, v.y, b.y);
    v.z = fmaf(a.z, v.z, b.z);
    v.w = fmaf(a.w, v.w, b.w);
    float* p = agg + (size_t)dst * DIM + q;
    unsafeAtomicAdd(p + 0, v.x);
    unsafeAtomicAdd(p + 1, v.y);
    unsafeAtomicAdd(p + 2, v.z);
    unsafeAtomicAdd(p + 3, v.w);
}

// ---------------- node MLP, layer 1 (input 16-dim, no BN on input) ----------------
// hout = relu( relu((x+agg) @ Wa + ba) @ Wb + bb )
__global__ void node1_k(const float* __restrict__ x, const float* __restrict__ agg,
                        float* __restrict__ hout,
                        const float* __restrict__ Wa, const float* __restrict__ ba,
                        const float* __restrict__ Wb, const float* __restrict__ bb,
                        int n_nodes) {
    int i = blockIdx.x * blockDim.x + threadIdx.x;
    if (i >= n_nodes) return;
    float u[NF];
    const float4* xv = (const float4*)(x + (size_t)i * NF);
    const float4* av = (const float4*)(agg + (size_t)i * NF);
#pragma unroll
    for (int q = 0; q < NF / 4; ++q) {
        float4 a = xv[q], b = av[q];
        u[q * 4 + 0] = a.x + b.x;
        u[q * 4 + 1] = a.y + b.y;
        u[q * 4 + 2] = a.z + b.z;
        u[q * 4 + 3] = a.w + b.w;
    }
    float t[DIM];
#pragma unroll
    for (int j = 0; j < DIM; ++j) {
        float acc = ba[j];
#pragma unroll
        for (int k = 0; k < NF; ++k) acc = fmaf(u[k], Wa[k * DIM + j], acc);
        t[j] = fmaxf(acc, 0.0f);
    }
    float4* ov = (float4*)(hout + (size_t)i * DIM);
#pragma unroll
    for (int j4 = 0; j4 < DIM; j4 += 4) {
        float accs[4];
#pragma unroll
        for (int m = 0; m < 4; ++m) {
            float acc = bb[j4 + m];
#pragma unroll
            for (int k = 0; k < DIM; ++k) acc = fmaf(t[k], Wb[k * DIM + j4 + m], acc);
            accs[m] = fmaxf(acc, 0.0f);
        }
        float4 o;
        o.x = accs[0]; o.y = accs[1]; o.z = accs[2]; o.w = accs[3];
        ov[j4 / 4] = o;
    }
}

// ---------------- node MLP, layers 2/3 (input 32-dim, BN applied to self-term) ----------------
// aggout holds agg on entry; result written in-place (same index -> thread-local, safe).
__global__ void node32_k(const float* __restrict__ hin, float* aggout,
                         const float* __restrict__ ab,
                         const float* __restrict__ Wa, const float* __restrict__ ba,
                         const float* __restrict__ Wb, const float* __restrict__ bb,
                         int n_nodes) {
    int i = blockIdx.x * blockDim.x + threadIdx.x;
    if (i >= n_nodes) return;
    float u[DIM];
    const float4* hv = (const float4*)(hin + (size_t)i * DIM);
    const float4* av = (const float4*)(aggout + (size_t)i * DIM);
#pragma unroll
    for (int q = 0; q < DIM / 4; ++q) {
        float4 h4 = hv[q];
        float4 g4 = av[q];
        float4 a4 = *(const float4*)(ab + q * 4);
        float4 b4 = *(const float4*)(ab + DIM + q * 4);
        u[q * 4 + 0] = fmaf(a4.x, h4.x, b4.x) + g4.x;
        u[q * 4 + 1] = fmaf(a4.y, h4.y, b4.y) + g4.y;
        u[q * 4 + 2] = fmaf(a4.z, h4.z, b4.z) + g4.z;
        u[q * 4 + 3] = fmaf(a4.w, h4.w, b4.w) + g4.w;
    }
    float t[DIM];
#pragma unroll
    for (int j = 0; j < DIM; ++j) {
        float acc = ba[j];
#pragma unroll
        for (int k = 0; k < DIM; ++k) acc = fmaf(u[k], Wa[k * DIM + j], acc);
        t[j] = fmaxf(acc, 0.0f);
    }
    float4* ov = (float4*)(aggout + (size_t)i * DIM);
#pragma unroll
    for (int j4 = 0; j4 < DIM; j4 += 4) {
        float accs[4];
#pragma unroll
        for (int m = 0; m < 4; ++m) {
            float acc = bb[j4 + m];
#pragma unroll
            for (int k = 0; k < DIM; ++k) acc = fmaf(t[k], Wb[k * DIM + j4 + m], acc);
            accs[m] = fmaxf(acc, 0.0f);
        }
        float4 o;
        o.x = accs[0]; o.y = accs[1]; o.z = accs[2]; o.w = accs[3];
        ov[j4 / 4] = o;
    }
}

// ---------------- per-column sum / sumsq over all nodes (for BN stats) ----------------
// sums[0..31] = sum, sums[32..63] = sumsq  (must be zeroed before)
__global__ void colstats_k(const float* __restrict__ h, float* __restrict__ sums,
                           int n_nodes) {
    int c = threadIdx.x & 31;
    int rowgrp = blockIdx.x * (blockDim.x >> 5) + (threadIdx.x >> 5);
    int stride = gridDim.x * (blockDim.x >> 5);
    float s = 0.0f, ss = 0.0f;
    for (int r = rowgrp; r < n_nodes; r += stride) {
        float v = h[(size_t)r * DIM + c];
        s += v;
        ss += v * v;
    }
    // lanes l and l^32 hold the same channel c -> combine
    s += __shfl_xor(s, 32);
    ss += __shfl_xor(ss, 32);
    if ((threadIdx.x & 32) == 0) {
        unsafeAtomicAdd(&sums[c], s);
        unsafeAtomicAdd(&sums[DIM + c], ss);
    }
}

// ---------------- BN finalize: a = gamma*rsqrt(var+eps), b = beta - a*mean ----------------
__global__ void bn_fin_k(const float* __restrict__ sums, const float* __restrict__ gamma,
                         const float* __restrict__ beta, float* __restrict__ ab,
                         float inv_n) {
    int c = threadIdx.x;
    if (c >= DIM) return;
    float mean = sums[c] * inv_n;
    float var = sums[DIM + c] * inv_n - mean * mean;
    float a = gamma[c] * rsqrtf(var + 1e-5f);
    ab[c] = a;
    ab[DIM + c] = beta[c] - a * mean;
}

// ---------------- sum-pool (64 nodes/graph) + final linear (32->2) + log_softmax ----------------
__global__ void pool_head_k(const float* __restrict__ h, const float* __restrict__ ab3,
                            const float* __restrict__ Wf, const float* __restrict__ bf,
                            float* __restrict__ out, int n_graphs) {
    int g = blockIdx.x;
    if (g >= n_graphs) return;
    int lane = threadIdx.x;           // 64 threads = 1 wave
    int c = lane & 31;
    int half = lane >> 5;             // half 0: nodes 0..31, half 1: nodes 32..63
    const float* base = h + ((size_t)g * 64 + (size_t)half * 32) * DIM;
    float s = 0.0f;
#pragma unroll
    for (int n = 0; n < 32; ++n) s += base[(size_t)n * DIM + c];
    s += __shfl_xor(s, 32);           // full 64-node sum for channel c
    // sum of bn(y) over 64 nodes = a*sum(y) + 64*b
    float a = ab3[c], b = ab3[DIM + c];
    s = fmaf(a, s, 64.0f * b);
    float p0 = s * Wf[c * 2 + 0];
    float p1 = s * Wf[c * 2 + 1];
#pragma unroll
    for (int o = 16; o > 0; o >>= 1) {
        p0 += __shfl_xor(p0, o);
        p1 += __shfl_xor(p1, o);
    }
    if (lane == 0) {
        float z0 = p0 + bf[0];
        float z1 = p1 + bf[1];
        float m = fmaxf(z0, z1);
        float lse = m + logf(expf(z0 - m) + expf(z1 - m));
        out[(size_t)g * 2 + 0] = z0 - lse;
        out[(size_t)g * 2 + 1] = z1 - lse;
    }
}

extern "C" void kernel_launch(void* const* d_in, const int* in_sizes, int n_in,
                              void* d_out, int out_size, void* d_ws, size_t ws_size,
                              hipStream_t stream) {
    const float* x  = (const float*)d_in[0];
    const int*   ei = (const int*)d_in[1];
    // d_in[2] = batch (scalar); derive sizes from in_sizes instead.
    const float* W1a = (const float*)d_in[3];
    const float* b1a = (const float*)d_in[4];
    const float* W1b = (const float*)d_in[5];
    const float* b1b = (const float*)d_in[6];
    const float* W2a = (const float*)d_in[7];
    const float* b2a = (const float*)d_in[8];
    const float* W2b = (const float*)d_in[9];
    const float* b2b = (const float*)d_in[10];
    const float* W3a = (const float*)d_in[11];
    const float* b3a = (const float*)d_in[12];
    const float* W3b = (const float*)d_in[13];
    const float* b3b = (const float*)d_in[14];
    const float* g1  = (const float*)d_in[15];
    const float* be1 = (const float*)d_in[16];
    const float* g2  = (const float*)d_in[17];
    const float* be2 = (const float*)d_in[18];
    const float* g3  = (const float*)d_in[19];
    const float* be3 = (const float*)d_in[20];
    const float* Wf  = (const float*)d_in[21];
    const float* bf  = (const float*)d_in[22];
    float* out = (float*)d_out;

    int n_nodes  = in_sizes[0] / NF;       // 524288
    int n_edges  = in_sizes[1] / 2;        // 8388608
    int n_graphs = n_nodes / 64;           // 8192
    float inv_n = 1.0f / (float)n_nodes;

    char* ws = (char*)d_ws;
    size_t region = (size_t)n_nodes * DIM * sizeof(float);   // 64 MB
    float* A = (float*)ws;                  // agg1(16d) -> agg2 -> h2
    float* B = (float*)(ws + region);       // h1 -> agg3 -> h3
    float* stats = (float*)(ws + 2 * region);
    float* sums1 = stats;        float* ab1 = stats + 64;
    float* sums2 = stats + 128;  float* ab2 = stats + 192;
    float* sums3 = stats + 256;  float* ab3 = stats + 320;

    const int BT = 256;
    int node_blocks = (n_nodes + BT - 1) / BT;
    int sc16_blocks = (n_edges * 4 + BT - 1) / BT;
    int sc32_blocks = (n_edges * 8 + BT - 1) / BT;

    hipMemsetAsync(stats, 0, 384 * sizeof(float), stream);

    // ---- layer 1 ----
    hipMemsetAsync(A, 0, (size_t)n_nodes * NF * sizeof(float), stream);
    scatter16_k<<<sc16_blocks, BT, 0, stream>>>(x, ei, A, n_edges);
    node1_k<<<node_blocks, BT, 0, stream>>>(x, A, B, W1a, b1a, W1b, b1b, n_nodes);
    colstats_k<<<1024, BT, 0, stream>>>(B, sums1, n_nodes);
    bn_fin_k<<<1, 64, 0, stream>>>(sums1, g1, be1, ab1, inv_n);

    // ---- layer 2 ----
    hipMemsetAsync(A, 0, region, stream);
    scatter32_bn_k<<<sc32_blocks, BT, 0, stream>>>(B, ei, ab1, A, n_edges);
    node32_k<<<node_blocks, BT, 0, stream>>>(B, A, ab1, W2a, b2a, W2b, b2b, n_nodes);  // h2 -> A
    colstats_k<<<1024, BT, 0, stream>>>(A, sums2, n_nodes);
    bn_fin_k<<<1, 64, 0, stream>>>(sums2, g2, be2, ab2, inv_n);

    // ---- layer 3 ----
    hipMemsetAsync(B, 0, region, stream);
    scatter32_bn_k<<<sc32_blocks, BT, 0, stream>>>(A, ei, ab2, B, n_edges);
    node32_k<<<node_blocks, BT, 0, stream>>>(A, B, ab2, W3a, b3a, W3b, b3b, n_nodes);  // h3 -> B
    colstats_k<<<1024, BT, 0, stream>>>(B, sums3, n_nodes);
    bn_fin_k<<<1, 64, 0, stream>>>(sums3, g3, be3, ab3, inv_n);

    // ---- pool + head ----
    pool_head_k<<<n_graphs, 64, 0, stream>>>(B, ab3, Wf, bf, out, n_graphs);
}

// Round 2
// 1863.874 us; speedup vs baseline: 4.8463x; 4.8463x over previous
//
#include <hip/hip_runtime.h>
#include <cstdint>
#include <cstddef>

#define NF 16
#define DIM 32

// ================= CSR build =================

// deg[dst]++ for every edge
__global__ void hist_k(const int* __restrict__ ei, int* __restrict__ deg, int n_edges) {
    int e = blockIdx.x * blockDim.x + threadIdx.x;
    if (e >= n_edges) return;
    int dst = ei[n_edges + e];
    atomicAdd(&deg[dst], 1);
}

// block-level exclusive scan: each block handles 1024 ints (256 thr x int4)
__global__ void scan1_k(const int* __restrict__ deg, int* __restrict__ rp,
                        int* __restrict__ bsum) {
    __shared__ int sh[256];
    int t = threadIdx.x;
    int base = blockIdx.x * 1024 + t * 4;
    int4 d = *(const int4*)(deg + base);
    int s = d.x + d.y + d.z + d.w;
    sh[t] = s;
    __syncthreads();
    for (int o = 1; o < 256; o <<= 1) {
        int v = 0;
        if (t >= o) v = sh[t - o];
        __syncthreads();
        if (t >= o) sh[t] += v;
        __syncthreads();
    }
    int excl = sh[t] - s;
    if (t == 255) bsum[blockIdx.x] = sh[255];
    rp[base + 0] = excl;
    rp[base + 1] = excl + d.x;
    rp[base + 2] = excl + d.x + d.y;
    rp[base + 3] = excl + d.x + d.y + d.z;
}

// scan the 512 block sums in one block; write exclusive offsets in-place, total -> rp[n]
__global__ void scan2_k(int* __restrict__ bsum, int* __restrict__ rp, int nb, int n) {
    __shared__ int sh[512];
    int t = threadIdx.x;
    int s = (t < nb) ? bsum[t] : 0;
    sh[t] = s;
    __syncthreads();
    for (int o = 1; o < 512; o <<= 1) {
        int v = 0;
        if (t >= o) v = sh[t - o];
        __syncthreads();
        if (t >= o) sh[t] += v;
        __syncthreads();
    }
    if (t < nb) bsum[t] = sh[t] - s;   // exclusive
    if (t == nb - 1) rp[n] = sh[t];    // total edges
}

// add block offsets
__global__ void scan3_k(int* __restrict__ rp, const int* __restrict__ bsum) {
    int t = threadIdx.x;
    int base = blockIdx.x * 1024 + t * 4;
    int off = bsum[blockIdx.x];
    rp[base + 0] += off;
    rp[base + 1] += off;
    rp[base + 2] += off;
    rp[base + 3] += off;
}

// csr_src[cursor[dst]++] = src
__global__ void fill_k(const int* __restrict__ ei, int* __restrict__ cursor,
                       int* __restrict__ csr_src, int n_edges) {
    int e = blockIdx.x * blockDim.x + threadIdx.x;
    if (e >= n_edges) return;
    int src = ei[e];
    int dst = ei[n_edges + e];
    int pos = atomicAdd(&cursor[dst], 1);
    csr_src[pos] = src;
}

// ================= gathers (atomic-free) =================

// 16-dim: 4 lanes per node, lane handles 4 channels
__global__ void gather16_k(const float* __restrict__ x, const int* __restrict__ rp,
                           const int* __restrict__ csr, float* __restrict__ agg,
                           int n_nodes) {
    int tid = blockIdx.x * blockDim.x + threadIdx.x;
    int i = tid >> 2;
    if (i >= n_nodes) return;
    int q = (tid & 3) * 4;
    int k = rp[i], e = rp[i + 1];
    float4 acc = make_float4(0.f, 0.f, 0.f, 0.f);
    for (; k + 1 < e; k += 2) {
        int s1 = csr[k], s2 = csr[k + 1];
        float4 v1 = *(const float4*)(x + (size_t)s1 * NF + q);
        float4 v2 = *(const float4*)(x + (size_t)s2 * NF + q);
        acc.x += v1.x + v2.x; acc.y += v1.y + v2.y;
        acc.z += v1.z + v2.z; acc.w += v1.w + v2.w;
    }
    if (k < e) {
        int s1 = csr[k];
        float4 v1 = *(const float4*)(x + (size_t)s1 * NF + q);
        acc.x += v1.x; acc.y += v1.y; acc.z += v1.z; acc.w += v1.w;
    }
    *(float4*)(agg + (size_t)i * NF + q) = acc;
}

// 32-dim: 8 lanes per node
__global__ void gather32_k(const float* __restrict__ h, const int* __restrict__ rp,
                           const int* __restrict__ csr, float* __restrict__ agg,
                           int n_nodes) {
    int tid = blockIdx.x * blockDim.x + threadIdx.x;
    int i = tid >> 3;
    if (i >= n_nodes) return;
    int q = (tid & 7) * 4;
    int k = rp[i], e = rp[i + 1];
    float4 acc = make_float4(0.f, 0.f, 0.f, 0.f);
    for (; k + 1 < e; k += 2) {
        int s1 = csr[k], s2 = csr[k + 1];
        float4 v1 = *(const float4*)(h + (size_t)s1 * DIM + q);
        float4 v2 = *(const float4*)(h + (size_t)s2 * DIM + q);
        acc.x += v1.x + v2.x; acc.y += v1.y + v2.y;
        acc.z += v1.z + v2.z; acc.w += v1.w + v2.w;
    }
    if (k < e) {
        int s1 = csr[k];
        float4 v1 = *(const float4*)(h + (size_t)s1 * DIM + q);
        acc.x += v1.x; acc.y += v1.y; acc.z += v1.z; acc.w += v1.w;
    }
    *(float4*)(agg + (size_t)i * DIM + q) = acc;
}

// ================= node MLPs =================

// layer 1: hout = relu( relu((x+agg) @ Wa + ba) @ Wb + bb )
__global__ void node1_k(const float* __restrict__ x, const float* __restrict__ agg,
                        float* __restrict__ hout,
                        const float* __restrict__ Wa, const float* __restrict__ ba,
                        const float* __restrict__ Wb, const float* __restrict__ bb,
                        int n_nodes) {
    int i = blockIdx.x * blockDim.x + threadIdx.x;
    if (i >= n_nodes) return;
    float u[NF];
    const float4* xv = (const float4*)(x + (size_t)i * NF);
    const float4* av = (const float4*)(agg + (size_t)i * NF);
#pragma unroll
    for (int q = 0; q < NF / 4; ++q) {
        float4 a = xv[q], b = av[q];
        u[q * 4 + 0] = a.x + b.x;
        u[q * 4 + 1] = a.y + b.y;
        u[q * 4 + 2] = a.z + b.z;
        u[q * 4 + 3] = a.w + b.w;
    }
    float t[DIM];
#pragma unroll
    for (int j = 0; j < DIM; ++j) {
        float acc = ba[j];
#pragma unroll
        for (int k = 0; k < NF; ++k) acc = fmaf(u[k], Wa[k * DIM + j], acc);
        t[j] = fmaxf(acc, 0.0f);
    }
    float4* ov = (float4*)(hout + (size_t)i * DIM);
#pragma unroll
    for (int j4 = 0; j4 < DIM; j4 += 4) {
        float accs[4];
#pragma unroll
        for (int m = 0; m < 4; ++m) {
            float acc = bb[j4 + m];
#pragma unroll
            for (int k = 0; k < DIM; ++k) acc = fmaf(t[k], Wb[k * DIM + j4 + m], acc);
            accs[m] = fmaxf(acc, 0.0f);
        }
        float4 o;
        o.x = accs[0]; o.y = accs[1]; o.z = accs[2]; o.w = accs[3];
        ov[j4 / 4] = o;
    }
}

// layers 2/3: u = a*(h_i + agg) + (1+deg)*b  (BN folded); in-place over agg
__global__ void node32_k(const float* __restrict__ hin, float* aggout,
                         const float* __restrict__ ab, const int* __restrict__ rp,
                         const float* __restrict__ Wa, const float* __restrict__ ba,
                         const float* __restrict__ Wb, const float* __restrict__ bb,
                         int n_nodes) {
    int i = blockIdx.x * blockDim.x + threadIdx.x;
    if (i >= n_nodes) return;
    float degp1 = (float)(rp[i + 1] - rp[i] + 1);
    float u[DIM];
    const float4* hv = (const float4*)(hin + (size_t)i * DIM);
    const float4* av = (const float4*)(aggout + (size_t)i * DIM);
#pragma unroll
    for (int q = 0; q < DIM / 4; ++q) {
        float4 h4 = hv[q];
        float4 g4 = av[q];
        float4 a4 = *(const float4*)(ab + q * 4);
        float4 b4 = *(const float4*)(ab + DIM + q * 4);
        u[q * 4 + 0] = fmaf(a4.x, h4.x + g4.x, degp1 * b4.x);
        u[q * 4 + 1] = fmaf(a4.y, h4.y + g4.y, degp1 * b4.y);
        u[q * 4 + 2] = fmaf(a4.z, h4.z + g4.z, degp1 * b4.z);
        u[q * 4 + 3] = fmaf(a4.w, h4.w + g4.w, degp1 * b4.w);
    }
    float t[DIM];
#pragma unroll
    for (int j = 0; j < DIM; ++j) {
        float acc = ba[j];
#pragma unroll
        for (int k = 0; k < DIM; ++k) acc = fmaf(u[k], Wa[k * DIM + j], acc);
        t[j] = fmaxf(acc, 0.0f);
    }
    float4* ov = (float4*)(aggout + (size_t)i * DIM);
#pragma unroll
    for (int j4 = 0; j4 < DIM; j4 += 4) {
        float accs[4];
#pragma unroll
        for (int m = 0; m < 4; ++m) {
            float acc = bb[j4 + m];
#pragma unroll
            for (int k = 0; k < DIM; ++k) acc = fmaf(t[k], Wb[k * DIM + j4 + m], acc);
            accs[m] = fmaxf(acc, 0.0f);
        }
        float4 o;
        o.x = accs[0]; o.y = accs[1]; o.z = accs[2]; o.w = accs[3];
        ov[j4 / 4] = o;
    }
}

// ================= BN stats =================

__global__ void colstats_k(const float* __restrict__ h, float* __restrict__ sums,
                           int n_nodes) {
    int c = threadIdx.x & 31;
    int rowgrp = blockIdx.x * (blockDim.x >> 5) + (threadIdx.x >> 5);
    int stride = gridDim.x * (blockDim.x >> 5);
    float s = 0.0f, ss = 0.0f;
    for (int r = rowgrp; r < n_nodes; r += stride) {
        float v = h[(size_t)r * DIM + c];
        s += v;
        ss += v * v;
    }
    s += __shfl_xor(s, 32);
    ss += __shfl_xor(ss, 32);
    if ((threadIdx.x & 32) == 0) {
        unsafeAtomicAdd(&sums[c], s);
        unsafeAtomicAdd(&sums[DIM + c], ss);
    }
}

__global__ void bn_fin_k(const float* __restrict__ sums, const float* __restrict__ gamma,
                         const float* __restrict__ beta, float* __restrict__ ab,
                         float inv_n) {
    int c = threadIdx.x;
    if (c >= DIM) return;
    float mean = sums[c] * inv_n;
    float var = sums[DIM + c] * inv_n - mean * mean;
    float a = gamma[c] * rsqrtf(var + 1e-5f);
    ab[c] = a;
    ab[DIM + c] = beta[c] - a * mean;
}

// ================= pool + head =================

__global__ void pool_head_k(const float* __restrict__ h, const float* __restrict__ ab3,
                            const float* __restrict__ Wf, const float* __restrict__ bf,
                            float* __restrict__ out, int n_graphs) {
    int g = blockIdx.x;
    if (g >= n_graphs) return;
    int lane = threadIdx.x;
    int c = lane & 31;
    int half = lane >> 5;
    const float* base = h + ((size_t)g * 64 + (size_t)half * 32) * DIM;
    float s = 0.0f;
#pragma unroll
    for (int n = 0; n < 32; ++n) s += base[(size_t)n * DIM + c];
    s += __shfl_xor(s, 32);
    float a = ab3[c], b = ab3[DIM + c];
    s = fmaf(a, s, 64.0f * b);
    float p0 = s * Wf[c * 2 + 0];
    float p1 = s * Wf[c * 2 + 1];
#pragma unroll
    for (int o = 16; o > 0; o >>= 1) {
        p0 += __shfl_xor(p0, o);
        p1 += __shfl_xor(p1, o);
    }
    if (lane == 0) {
        float z0 = p0 + bf[0];
        float z1 = p1 + bf[1];
        float m = fmaxf(z0, z1);
        float lse = m + logf(expf(z0 - m) + expf(z1 - m));
        out[(size_t)g * 2 + 0] = z0 - lse;
        out[(size_t)g * 2 + 1] = z1 - lse;
    }
}

extern "C" void kernel_launch(void* const* d_in, const int* in_sizes, int n_in,
                              void* d_out, int out_size, void* d_ws, size_t ws_size,
                              hipStream_t stream) {
    const float* x  = (const float*)d_in[0];
    const int*   ei = (const int*)d_in[1];
    const float* W1a = (const float*)d_in[3];
    const float* b1a = (const float*)d_in[4];
    const float* W1b = (const float*)d_in[5];
    const float* b1b = (const float*)d_in[6];
    const float* W2a = (const float*)d_in[7];
    const float* b2a = (const float*)d_in[8];
    const float* W2b = (const float*)d_in[9];
    const float* b2b = (const float*)d_in[10];
    const float* W3a = (const float*)d_in[11];
    const float* b3a = (const float*)d_in[12];
    const float* W3b = (const float*)d_in[13];
    const float* b3b = (const float*)d_in[14];
    const float* g1  = (const float*)d_in[15];
    const float* be1 = (const float*)d_in[16];
    const float* g2  = (const float*)d_in[17];
    const float* be2 = (const float*)d_in[18];
    const float* g3  = (const float*)d_in[19];
    const float* be3 = (const float*)d_in[20];
    const float* Wf  = (const float*)d_in[21];
    const float* bf  = (const float*)d_in[22];
    float* out = (float*)d_out;

    int n_nodes  = in_sizes[0] / NF;       // 524288
    int n_edges  = in_sizes[1] / 2;        // 8388608
    int n_graphs = n_nodes / 64;           // 8192
    float inv_n = 1.0f / (float)n_nodes;

    char* ws = (char*)d_ws;
    size_t off = 0;
    float* A       = (float*)(ws + off); off += (size_t)n_nodes * DIM * sizeof(float);   // 64 MB
    float* B       = (float*)(ws + off); off += (size_t)n_nodes * DIM * sizeof(float);   // 64 MB
    int*   csr_src = (int*)(ws + off);   off += (size_t)n_edges * sizeof(int);           // 33.5 MB
    int*   rp      = (int*)(ws + off);   off += ((size_t)n_nodes + 64) * sizeof(int);    // ~2 MB
    int*   cursor  = (int*)(ws + off);   off += ((size_t)n_nodes + 64) * sizeof(int);
    int*   deg     = (int*)(ws + off);   off += (size_t)n_nodes * sizeof(int);
    int*   bsum    = (int*)(ws + off);   off += 1024 * sizeof(int);
    float* stats   = (float*)(ws + off);
    float* sums1 = stats;        float* ab1 = stats + 64;
    float* sums2 = stats + 128;  float* ab2 = stats + 192;
    float* sums3 = stats + 256;  float* ab3 = stats + 320;

    const int BT = 256;
    int node_blocks = (n_nodes + BT - 1) / BT;
    int edge_blocks = (n_edges + BT - 1) / BT;
    int g16_blocks  = (n_nodes * 4 + BT - 1) / BT;
    int g32_blocks  = (n_nodes * 8 + BT - 1) / BT;
    int nb1 = n_nodes / 1024;  // 512 (n_nodes divisible by 1024)

    hipMemsetAsync(stats, 0, 384 * sizeof(float), stream);

    // ---- CSR build ----
    hipMemsetAsync(deg, 0, (size_t)n_nodes * sizeof(int), stream);
    hist_k<<<edge_blocks, BT, 0, stream>>>(ei, deg, n_edges);
    scan1_k<<<nb1, 256, 0, stream>>>(deg, rp, bsum);
    scan2_k<<<1, 512, 0, stream>>>(bsum, rp, nb1, n_nodes);
    scan3_k<<<nb1, 256, 0, stream>>>(rp, bsum);
    hipMemcpyAsync(cursor, rp, (size_t)n_nodes * sizeof(int), hipMemcpyDeviceToDevice, stream);
    fill_k<<<edge_blocks, BT, 0, stream>>>(ei, cursor, csr_src, n_edges);

    // ---- layer 1 ----
    gather16_k<<<g16_blocks, BT, 0, stream>>>(x, rp, csr_src, A, n_nodes);
    node1_k<<<node_blocks, BT, 0, stream>>>(x, A, B, W1a, b1a, W1b, b1b, n_nodes);
    colstats_k<<<1024, BT, 0, stream>>>(B, sums1, n_nodes);
    bn_fin_k<<<1, 64, 0, stream>>>(sums1, g1, be1, ab1, inv_n);

    // ---- layer 2 ----
    gather32_k<<<g32_blocks, BT, 0, stream>>>(B, rp, csr_src, A, n_nodes);
    node32_k<<<node_blocks, BT, 0, stream>>>(B, A, ab1, rp, W2a, b2a, W2b, b2b, n_nodes);
    colstats_k<<<1024, BT, 0, stream>>>(A, sums2, n_nodes);
    bn_fin_k<<<1, 64, 0, stream>>>(sums2, g2, be2, ab2, inv_n);

    // ---- layer 3 ----
    gather32_k<<<g32_blocks, BT, 0, stream>>>(A, rp, csr_src, B, n_nodes);
    node32_k<<<node_blocks, BT, 0, stream>>>(A, B, ab2, rp, W3a, b3a, W3b, b3b, n_nodes);
    colstats_k<<<1024, BT, 0, stream>>>(B, sums3, n_nodes);
    bn_fin_k<<<1, 64, 0, stream>>>(sums3, g3, be3, ab3, inv_n);

    // ---- pool + head ----
    pool_head_k<<<n_graphs, 64, 0, stream>>>(B, ab3, Wf, bf, out, n_graphs);
}